// Round 8
// baseline (125.771 us; speedup 1.0000x reference)
//
#include <hip/hip_runtime.h>
#include <hip/hip_fp16.h>
#include <utility>

// ============================================================================
// CG tensor product + complex weight contraction, fused per batch element.
// LMAX=5, TAU_PRE=16, TAU=16, B=256.
// Inputs (dict order): f0,w0,...,f5,w5. f_l:[256,16,2l+1,2] f32; w_l:[16,C_l,2] f32
// Output: concat of out_l [256,16,2l+1,2] f32 (294912 elems).
//
// Block=(b,L), 256 thr (4 waves), WAVE-INDEPENDENT main loop:
//  wave w's MFMA K-window [64w,64w+64) reads exactly the frag rows written by
//  its own 64 threads (XOR swizzle stays inside each 256B per-wave window), so
//  NO barrier / NO double-buffer is needed in the main loop — same-wave LDS
//  RAW is ordered by lgkmcnt. Per triple: phase1 (packed-f16 CG contract,
//  compile-time coeffs) -> MFMA f16 (complex via A'=(wR,-wI), A''=(wI,wR)).
//  One barrier total, before the cross-wave epilogue reduce (separate LDS).
// w pre-converted to f16 in d_ws by wconv_kernel (per launch).
// ============================================================================

using f32x4 = __attribute__((ext_vector_type(4))) float;
using f16x8 = __attribute__((ext_vector_type(8))) _Float16;

constexpr int OUTOFF_[6]  = {0, 8192, 32768, 73728, 131072, 204800};
constexpr int NUMCOLS_[6] = {1536, 2560, 3328, 3584, 3584, 3072};
constexpr int FOFFH_[6]   = {0, 16, 64, 144, 256, 400};   // u32 (packed cplx) offsets
// f16-element offsets of w_l inside d_ws (16*C_l*2 elements each)
constexpr int WOFF_[6]    = {0, 49152, 131072, 237568, 352256, 466944};

constexpr int TRI_N[6] = {6, 10, 13, 14, 14, 12};
constexpr int TRI_L1[6][14] = {
    {0,1,2,3,4,5, 0,0,0,0,0,0,0,0},
    {1,1,2,2,3,3,4,4,5,5, 0,0,0,0},
    {1,2,2,2,3,3,3,4,4,4,5,5,5, 0},
    {2,2,3,3,3,3,4,4,4,4,5,5,5,5},
    {2,3,3,3,4,4,4,4,4,5,5,5,5,5},
    {3,3,4,4,4,4,5,5,5,5,5,5, 0,0}};
constexpr int TRI_L2[6][14] = {
    {0,1,2,3,4,5, 0,0,0,0,0,0,0,0},
    {0,1,1,2,2,3,3,4,4,5, 0,0,0,0},
    {1,0,1,2,1,2,3,2,3,4,3,4,5, 0},
    {1,2,0,1,2,3,1,2,3,4,2,3,4,5},
    {2,1,2,3,0,1,2,3,4,1,2,3,4,5},
    {2,3,1,2,3,4,0,1,2,3,4,5, 0,0}};

// ---------------- compile-time Clebsch-Gordan ----------------
constexpr double cfact(int n) { double r = 1.0; for (int i = 2; i <= n; ++i) r *= (double)i; return r; }

constexpr double csqrt(double x) {
    if (x <= 0.0) return 0.0;
    double g = x < 1.0 ? 1.0 : x;
    for (int i = 0; i < 200; ++i) {
        double n = 0.5 * (g + x / g);
        if (n == g) break;
        g = n;
    }
    return g;
}

constexpr double cg_c(int l1, int l2, int l, int m1, int m2, int m) {
    double pref = (2.0 * l + 1.0) * cfact(l + l1 - l2) * cfact(l - l1 + l2) *
                  cfact(l1 + l2 - l) / cfact(l1 + l2 + l + 1);
    pref *= cfact(l + m) * cfact(l - m) * cfact(l1 - m1) * cfact(l1 + m1) *
            cfact(l2 - m2) * cfact(l2 + m2);
    pref = csqrt(pref);
    int kmin = 0;
    if (l2 - l - m1 > kmin) kmin = l2 - l - m1;
    if (l1 + m2 - l > kmin) kmin = l1 + m2 - l;
    int kmax = l1 + l2 - l;
    if (l1 - m1 < kmax) kmax = l1 - m1;
    if (l2 + m2 < kmax) kmax = l2 + m2;
    double s = 0.0;
    for (int k = kmin; k <= kmax; ++k) {
        double d = cfact(k) * cfact(l1 + l2 - l - k) * cfact(l1 - m1 - k) *
                   cfact(l2 + m2 - k) * cfact(l - l2 + m1 + k) * cfact(l - l1 - m2 + k);
        s += ((k & 1) ? -1.0 : 1.0) / d;
    }
    return pref * s;
}

template <int L1, int L2, int L>
struct CGTab {
    static constexpr int N1 = 2 * L1 + 1, N2 = 2 * L2 + 1;
    struct T { float v[N1 * N2]; };
    static constexpr T build() {
        T t{};
        for (int m1 = -L1; m1 <= L1; ++m1)
            for (int m2 = -L2; m2 <= L2; ++m2) {
                int m = m1 + m2;
                double v = 0.0;
                if (m >= -L && m <= L) v = cg_c(L1, L2, L, m1, m2, m);
                t.v[(m1 + L1) * N2 + (m2 + L2)] = (float)v;
            }
        return t;
    }
    static constexpr T TAB = build();
};

// ---------------- w -> f16 pre-convert ----------------
__global__ __launch_bounds__(256)
void wconv_kernel(const float* __restrict__ w0, const float* __restrict__ w1,
                  const float* __restrict__ w2, const float* __restrict__ w3,
                  const float* __restrict__ w4, const float* __restrict__ w5,
                  unsigned short* __restrict__ dst)
{
    const int l = blockIdx.y;
    const float* srcs[6] = {w0, w1, w2, w3, w4, w5};
    const float* src = srcs[l];
    const int cnt = 16 * NUMCOLS_[l] * 2;
    const int i4 = (blockIdx.x * 256 + threadIdx.x) * 4;
    if (i4 < cnt) {
        const float4 v = *(const float4*)(src + i4);
        __half hx = __float2half(v.x), hy = __float2half(v.y);
        __half hz = __float2half(v.z), hw = __float2half(v.w);
        ushort4 o;
        o.x = *(unsigned short*)&hx; o.y = *(unsigned short*)&hy;
        o.z = *(unsigned short*)&hz; o.w = *(unsigned short*)&hw;
        *(ushort4*)(dst + WOFF_[l] + i4) = o;
    }
}

// ---------------- phase 1: packed-f16 CG contract -> LDS rows ----------------
template <int L, int L1, int L2>
__device__ __forceinline__ void do_phase1(const unsigned* __restrict__ sh_fh,
                                          char* __restrict__ frag, const int tid)
{
    constexpr int N1 = 2 * L1 + 1, N2 = 2 * L2 + 1, NK = 2 * L + 1, SH = L1 + L2 - L;
    const int i = tid >> 4, j = tid & 15;
    const unsigned* f1 = sh_fh + FOFFH_[L1] + i * N1;
    const unsigned* f2 = sh_fh + FOFFH_[L2] + j * N2;

    // hoisted per-triple forms (bit-ops on packed f16):
    //  axx = (ar,ar)  ayy = (ai,ai)  bv = (br,bi)  bsn = (-bi,br)
    unsigned axx[N1], ayy[N1], bv[N2], bsn[N2];
#pragma unroll
    for (int m = 0; m < N1; ++m) {
        const unsigned a = f1[m];
        const unsigned lo = a & 0xffffu, hi = a >> 16;
        axx[m] = lo | (lo << 16);
        ayy[m] = hi | (hi << 16);
    }
#pragma unroll
    for (int n = 0; n < N2; ++n) {
        const unsigned b = f2[n];
        bv[n] = b;
        bsn[n] = ((b >> 16) | (b << 16)) ^ 0x8000u;
    }

    const int ij4 = tid * 4;
#pragma unroll
    for (int k = 0; k < NK; ++k) {
        const int kk = k + SH;
        __half2 acc = __float2half2_rn(0.0f);
#pragma unroll
        for (int m1 = 0; m1 < N1; ++m1) {
            const int m2 = kk - m1;
            if (m2 >= 0 && m2 < N2) {  // compile-time after unroll
                const float c = CGTab<L1, L2, L>::TAB.v[m1 * N2 + m2];
                if (c != 0.f) {        // folded constant -> zero terms DCE'd
                    // p = (ar*br - ai*bi, ar*bi + ai*br)
                    const __half2 p = __hfma2(*(const __half2*)&ayy[m1],
                                              *(const __half2*)&bsn[m2],
                                              __hmul2(*(const __half2*)&axx[m1],
                                                      *(const __half2*)&bv[m2]));
                    acc = __hfma2(__float2half2_rn(c), p, acc);
                }
            }
        }
        *(__half2*)(frag + ((k * 1024 + ij4) ^ ((k & 7) << 4))) = acc;
    }
}

// ---------------- phase 2: MFMA (f16) consume one triple (same wave's rows) ----
template <int L>
__device__ __forceinline__ void do_mfma(const char* __restrict__ frag,
                                        const unsigned short* __restrict__ wh,
                                        const int cbase, const int wave,
                                        const int lane, f32x4& PR, f32x4& PI)
{
    constexpr int NK = 2 * L + 1;
    const int t = lane & 15, g = lane >> 4;
    int nc = lane & 15; if (nc > NK - 1) nc = NK - 1;   // clamped B col (dup, never read)
    const int C = NUMCOLS_[L];
#pragma unroll
    for (int ks = 0; ks < 4; ++ks) {
        const int c0 = wave * 64 + ks * 16 + 4 * g;     // complex col window (4 cols)
        // A: 4 complex w values = 8 f16 = 16B
        uint4 wa = *(const uint4*)(wh + (size_t)(t * C + cbase + c0) * 2);
        uint4 a1, a2;                                    // A' = (wR,-wI), A'' = (wI,wR)
        a1.x = wa.x ^ 0x80000000u; a1.y = wa.y ^ 0x80000000u;
        a1.z = wa.z ^ 0x80000000u; a1.w = wa.w ^ 0x80000000u;
        a2.x = (wa.x >> 16) | (wa.x << 16); a2.y = (wa.y >> 16) | (wa.y << 16);
        a2.z = (wa.z >> 16) | (wa.z << 16); a2.w = (wa.w >> 16) | (wa.w << 16);
        // B: 16B of interleaved (fR,fI) along ij for col nc — own wave's bytes
        const int byt = (nc * 1024 + c0 * 4) ^ ((nc & 7) << 4);
        const f16x8 B = *(const f16x8*)(frag + byt);
        PR = __builtin_amdgcn_mfma_f32_16x16x32_f16(*(const f16x8*)&a1, B, PR, 0, 0, 0);
        PI = __builtin_amdgcn_mfma_f32_16x16x32_f16(*(const f16x8*)&a2, B, PI, 0, 0, 0);
    }
}

// ---------------- step driver: phase1 -> mfma, NO barrier ----------------
template <int L, int IDX>
__device__ __forceinline__ void step(const unsigned* sh_fh, char* frag,
                                     const unsigned short* wh, const int tid,
                                     const int wave, const int lane,
                                     f32x4& PR, f32x4& PI)
{
    do_phase1<L, TRI_L1[L][IDX], TRI_L2[L][IDX]>(sh_fh, frag, tid);
    do_mfma<L>(frag, wh, IDX * 256, wave, lane, PR, PI);
}

template <int L, int... Is>
__device__ __forceinline__ void run_steps(std::integer_sequence<int, Is...>,
    const unsigned* sh_fh, char* frag, const unsigned short* wh,
    int tid, int wave, int lane, f32x4& PR, f32x4& PI)
{
    (step<L, Is>(sh_fh, frag, wh, tid, wave, lane, PR, PI), ...);
}

template <int L>
__device__ void run_l(const float* const* fs, const unsigned short* __restrict__ wh,
                      float* __restrict__ out, unsigned* sh_fh, char* frag, float* pb)
{
    const int b = blockIdx.x, tid = threadIdx.x;
    const int wave = tid >> 6, lane = tid & 63;

    // stage all f_l[b] into LDS as packed f16 complex (576 u32)
#pragma unroll
    for (int l = 0; l < 6; ++l) {
        const int cnt = 16 * (2 * l + 1);               // complex elements
        const float2* s2 = (const float2*)(fs[l] + (size_t)b * 32 * (2 * l + 1));
        if (tid < cnt) {
            const float2 v = s2[tid];
            const __half2 h = __floats2half2_rn(v.x, v.y);
            sh_fh[FOFFH_[l] + tid] = *(const unsigned*)&h;
        }
    }
    __syncthreads();

    f32x4 PR = {0.f, 0.f, 0.f, 0.f}, PI = {0.f, 0.f, 0.f, 0.f};

    run_steps<L>(std::make_integer_sequence<int, TRI_N[L]>{},
                 sh_fh, frag, wh, tid, wave, lane, PR, PI);

    // ---- epilogue: 4-wave partial sums via separate LDS region ----
    constexpr int NK = 2 * L + 1;
    {
        const int kcol = lane & 15, g = lane >> 4;   // D: col=lane&15 (k), row=4g+r (t)
#pragma unroll
        for (int r = 0; r < 4; ++r) {
            pb[(wave * 2 + 0) * 256 + (4 * g + r) * 16 + kcol] = PR[r];
            pb[(wave * 2 + 1) * 256 + (4 * g + r) * 16 + kcol] = PI[r];
        }
    }
    __syncthreads();

    if (tid < 16 * NK) {
        const int t = tid & 15, k = tid >> 4;
        float oR = 0.f, oI = 0.f;
#pragma unroll
        for (int w = 0; w < 4; ++w) {
            oR += pb[(w * 2 + 0) * 256 + t * 16 + k];
            oI += pb[(w * 2 + 1) * 256 + t * 16 + k];
        }
        float* op = out + OUTOFF_[L] + ((size_t)(b * 16 + t) * NK + k) * 2;
        op[0] = oR;
        op[1] = oI;
    }
}

__global__ __launch_bounds__(256, 6)
void update_kernel(const float* __restrict__ f0, const float* __restrict__ f1,
                   const float* __restrict__ f2, const float* __restrict__ f3,
                   const float* __restrict__ f4, const float* __restrict__ f5,
                   const unsigned short* __restrict__ wh,
                   float* __restrict__ out)
{
    __shared__ unsigned sh_fh[576];
    __shared__ __align__(16) char frag[11264];   // 11 rows x 1KB, single buffer
    __shared__ __align__(16) float pb[2048];     // epilogue partials (8KB)
    const float* fs[6] = {f0, f1, f2, f3, f4, f5};
    // Heavy-L-first dispatch: y=0 (dispatched first) -> L=5, ... y=5 -> L=0
    switch (blockIdx.y) {
        case 0: run_l<5>(fs, wh + WOFF_[5], out, sh_fh, frag, pb); break;
        case 1: run_l<4>(fs, wh + WOFF_[4], out, sh_fh, frag, pb); break;
        case 2: run_l<3>(fs, wh + WOFF_[3], out, sh_fh, frag, pb); break;
        case 3: run_l<2>(fs, wh + WOFF_[2], out, sh_fh, frag, pb); break;
        case 4: run_l<1>(fs, wh + WOFF_[1], out, sh_fh, frag, pb); break;
        default: run_l<0>(fs, wh + WOFF_[0], out, sh_fh, frag, pb); break;
    }
}

// ============================================================================
extern "C" void kernel_launch(void* const* d_in, const int* in_sizes, int n_in,
                              void* d_out, int out_size, void* d_ws, size_t ws_size,
                              hipStream_t stream)
{
    const float* f[6];
    const float* w[6];
    for (int l = 0; l < 6; ++l) {
        f[l] = (const float*)d_in[2 * l];      // f0,w0,f1,w1,... dict order
        w[l] = (const float*)d_in[2 * l + 1];
    }
    unsigned short* wh = (unsigned short*)d_ws;  // 565248 f16 = 1.13 MB

    // convert w to f16 (max segment 114688 f32 -> 112 blocks of 256x4)
    wconv_kernel<<<dim3(112, 6), dim3(256), 0, stream>>>(
        w[0], w[1], w[2], w[3], w[4], w[5], wh);

    update_kernel<<<dim3(256, 6), dim3(256), 0, stream>>>(
        f[0], f[1], f[2], f[3], f[4], f[5], wh, (float*)d_out);
}

// Round 9
// 112.532 us; speedup vs baseline: 1.1176x; 1.1176x over previous
//
#include <hip/hip_runtime.h>
#include <hip/hip_fp16.h>
#include <utility>

// ============================================================================
// CG tensor product + complex weight contraction, fused per batch element.
// LMAX=5, TAU_PRE=16, TAU=16, B=256.
// Inputs (dict order): f0,w0,...,f5,w5. f_l:[256,16,2l+1,2] f32; w_l:[16,C_l,2] f32
// Output: concat of out_l [256,16,2l+1,2] f32 (294912 elems).
//
// Block=(b,L), 256 thr (4 waves), WAVE-INDEPENDENT main loop:
//  wave w's MFMA K-window [64w,64w+64) reads exactly the frag rows written by
//  its own 64 threads (XOR swizzle stays inside each 256B per-wave window), so
//  NO barrier / NO double-buffer is needed in the main loop — same-wave LDS
//  RAW is ordered by lgkmcnt. Per triple: phase1 (packed-f16 CG contract,
//  compile-time coeffs) -> MFMA f16 (complex via A'=(wR,-wI), A''=(wI,wR)).
//  sched_barrier(0) at each step boundary stops cross-step load hoisting
//  (round-8 lesson: without it the compiler hoists all w loads -> 38MB spill).
//  One real barrier total, before the cross-wave epilogue reduce.
// w pre-converted to f16 in d_ws by wconv_kernel (per launch).
// ============================================================================

using f32x4 = __attribute__((ext_vector_type(4))) float;
using f16x8 = __attribute__((ext_vector_type(8))) _Float16;

constexpr int OUTOFF_[6]  = {0, 8192, 32768, 73728, 131072, 204800};
constexpr int NUMCOLS_[6] = {1536, 2560, 3328, 3584, 3584, 3072};
constexpr int FOFFH_[6]   = {0, 16, 64, 144, 256, 400};   // u32 (packed cplx) offsets
// f16-element offsets of w_l inside d_ws (16*C_l*2 elements each)
constexpr int WOFF_[6]    = {0, 49152, 131072, 237568, 352256, 466944};

constexpr int TRI_N[6] = {6, 10, 13, 14, 14, 12};
constexpr int TRI_L1[6][14] = {
    {0,1,2,3,4,5, 0,0,0,0,0,0,0,0},
    {1,1,2,2,3,3,4,4,5,5, 0,0,0,0},
    {1,2,2,2,3,3,3,4,4,4,5,5,5, 0},
    {2,2,3,3,3,3,4,4,4,4,5,5,5,5},
    {2,3,3,3,4,4,4,4,4,5,5,5,5,5},
    {3,3,4,4,4,4,5,5,5,5,5,5, 0,0}};
constexpr int TRI_L2[6][14] = {
    {0,1,2,3,4,5, 0,0,0,0,0,0,0,0},
    {0,1,1,2,2,3,3,4,4,5, 0,0,0,0},
    {1,0,1,2,1,2,3,2,3,4,3,4,5, 0},
    {1,2,0,1,2,3,1,2,3,4,2,3,4,5},
    {2,1,2,3,0,1,2,3,4,1,2,3,4,5},
    {2,3,1,2,3,4,0,1,2,3,4,5, 0,0}};

// ---------------- compile-time Clebsch-Gordan ----------------
constexpr double cfact(int n) { double r = 1.0; for (int i = 2; i <= n; ++i) r *= (double)i; return r; }

constexpr double csqrt(double x) {
    if (x <= 0.0) return 0.0;
    double g = x < 1.0 ? 1.0 : x;
    for (int i = 0; i < 200; ++i) {
        double n = 0.5 * (g + x / g);
        if (n == g) break;
        g = n;
    }
    return g;
}

constexpr double cg_c(int l1, int l2, int l, int m1, int m2, int m) {
    double pref = (2.0 * l + 1.0) * cfact(l + l1 - l2) * cfact(l - l1 + l2) *
                  cfact(l1 + l2 - l) / cfact(l1 + l2 + l + 1);
    pref *= cfact(l + m) * cfact(l - m) * cfact(l1 - m1) * cfact(l1 + m1) *
            cfact(l2 - m2) * cfact(l2 + m2);
    pref = csqrt(pref);
    int kmin = 0;
    if (l2 - l - m1 > kmin) kmin = l2 - l - m1;
    if (l1 + m2 - l > kmin) kmin = l1 + m2 - l;
    int kmax = l1 + l2 - l;
    if (l1 - m1 < kmax) kmax = l1 - m1;
    if (l2 + m2 < kmax) kmax = l2 + m2;
    double s = 0.0;
    for (int k = kmin; k <= kmax; ++k) {
        double d = cfact(k) * cfact(l1 + l2 - l - k) * cfact(l1 - m1 - k) *
                   cfact(l2 + m2 - k) * cfact(l - l2 + m1 + k) * cfact(l - l1 - m2 + k);
        s += ((k & 1) ? -1.0 : 1.0) / d;
    }
    return pref * s;
}

template <int L1, int L2, int L>
struct CGTab {
    static constexpr int N1 = 2 * L1 + 1, N2 = 2 * L2 + 1;
    struct T { float v[N1 * N2]; };
    static constexpr T build() {
        T t{};
        for (int m1 = -L1; m1 <= L1; ++m1)
            for (int m2 = -L2; m2 <= L2; ++m2) {
                int m = m1 + m2;
                double v = 0.0;
                if (m >= -L && m <= L) v = cg_c(L1, L2, L, m1, m2, m);
                t.v[(m1 + L1) * N2 + (m2 + L2)] = (float)v;
            }
        return t;
    }
    static constexpr T TAB = build();
};

// ---------------- w -> f16 pre-convert ----------------
__global__ __launch_bounds__(256)
void wconv_kernel(const float* __restrict__ w0, const float* __restrict__ w1,
                  const float* __restrict__ w2, const float* __restrict__ w3,
                  const float* __restrict__ w4, const float* __restrict__ w5,
                  unsigned short* __restrict__ dst)
{
    const int l = blockIdx.y;
    const float* srcs[6] = {w0, w1, w2, w3, w4, w5};
    const float* src = srcs[l];
    const int cnt = 16 * NUMCOLS_[l] * 2;
    const int i4 = (blockIdx.x * 256 + threadIdx.x) * 4;
    if (i4 < cnt) {
        const float4 v = *(const float4*)(src + i4);
        __half hx = __float2half(v.x), hy = __float2half(v.y);
        __half hz = __float2half(v.z), hw = __float2half(v.w);
        ushort4 o;
        o.x = *(unsigned short*)&hx; o.y = *(unsigned short*)&hy;
        o.z = *(unsigned short*)&hz; o.w = *(unsigned short*)&hw;
        *(ushort4*)(dst + WOFF_[l] + i4) = o;
    }
}

// ---------------- phase 1: packed-f16 CG contract -> LDS rows ----------------
template <int L, int L1, int L2>
__device__ __forceinline__ void do_phase1(const unsigned* __restrict__ sh_fh,
                                          char* __restrict__ frag, const int tid)
{
    constexpr int N1 = 2 * L1 + 1, N2 = 2 * L2 + 1, NK = 2 * L + 1, SH = L1 + L2 - L;
    const int i = tid >> 4, j = tid & 15;
    const unsigned* f1 = sh_fh + FOFFH_[L1] + i * N1;
    const unsigned* f2 = sh_fh + FOFFH_[L2] + j * N2;

    // hoisted per-triple forms (bit-ops on packed f16):
    //  axx = (ar,ar)  ayy = (ai,ai)  bv = (br,bi)  bsn = (-bi,br)
    unsigned axx[N1], ayy[N1], bv[N2], bsn[N2];
#pragma unroll
    for (int m = 0; m < N1; ++m) {
        const unsigned a = f1[m];
        const unsigned lo = a & 0xffffu, hi = a >> 16;
        axx[m] = lo | (lo << 16);
        ayy[m] = hi | (hi << 16);
    }
#pragma unroll
    for (int n = 0; n < N2; ++n) {
        const unsigned b = f2[n];
        bv[n] = b;
        bsn[n] = ((b >> 16) | (b << 16)) ^ 0x8000u;
    }

    const int ij4 = tid * 4;
#pragma unroll
    for (int k = 0; k < NK; ++k) {
        const int kk = k + SH;
        __half2 acc = __float2half2_rn(0.0f);
#pragma unroll
        for (int m1 = 0; m1 < N1; ++m1) {
            const int m2 = kk - m1;
            if (m2 >= 0 && m2 < N2) {  // compile-time after unroll
                const float c = CGTab<L1, L2, L>::TAB.v[m1 * N2 + m2];
                if (c != 0.f) {        // folded constant -> zero terms DCE'd
                    // p = (ar*br - ai*bi, ar*bi + ai*br)
                    const __half2 p = __hfma2(*(const __half2*)&ayy[m1],
                                              *(const __half2*)&bsn[m2],
                                              __hmul2(*(const __half2*)&axx[m1],
                                                      *(const __half2*)&bv[m2]));
                    acc = __hfma2(__float2half2_rn(c), p, acc);
                }
            }
        }
        *(__half2*)(frag + ((k * 1024 + ij4) ^ ((k & 7) << 4))) = acc;
    }
}

// ---------------- phase 2: MFMA (f16) consume one triple (same wave's rows) ----
template <int L>
__device__ __forceinline__ void do_mfma(const char* __restrict__ frag,
                                        const unsigned short* __restrict__ wh,
                                        const int cbase, const int wave,
                                        const int lane, f32x4& PR, f32x4& PI)
{
    constexpr int NK = 2 * L + 1;
    const int t = lane & 15, g = lane >> 4;
    int nc = lane & 15; if (nc > NK - 1) nc = NK - 1;   // clamped B col (dup, never read)
    const int C = NUMCOLS_[L];
#pragma unroll
    for (int ks = 0; ks < 4; ++ks) {
        const int c0 = wave * 64 + ks * 16 + 4 * g;     // complex col window (4 cols)
        // A: 4 complex w values = 8 f16 = 16B
        uint4 wa = *(const uint4*)(wh + (size_t)(t * C + cbase + c0) * 2);
        uint4 a1, a2;                                    // A' = (wR,-wI), A'' = (wI,wR)
        a1.x = wa.x ^ 0x80000000u; a1.y = wa.y ^ 0x80000000u;
        a1.z = wa.z ^ 0x80000000u; a1.w = wa.w ^ 0x80000000u;
        a2.x = (wa.x >> 16) | (wa.x << 16); a2.y = (wa.y >> 16) | (wa.y << 16);
        a2.z = (wa.z >> 16) | (wa.z << 16); a2.w = (wa.w >> 16) | (wa.w << 16);
        // B: 16B of interleaved (fR,fI) along ij for col nc — own wave's bytes
        const int byt = (nc * 1024 + c0 * 4) ^ ((nc & 7) << 4);
        const f16x8 B = *(const f16x8*)(frag + byt);
        PR = __builtin_amdgcn_mfma_f32_16x16x32_f16(*(const f16x8*)&a1, B, PR, 0, 0, 0);
        PI = __builtin_amdgcn_mfma_f32_16x16x32_f16(*(const f16x8*)&a2, B, PI, 0, 0, 0);
    }
}

// ---------------- step driver: phase1 -> mfma, sched-fenced, NO barrier ------
template <int L, int IDX>
__device__ __forceinline__ void step(const unsigned* sh_fh, char* frag,
                                     const unsigned short* wh, const int tid,
                                     const int wave, const int lane,
                                     f32x4& PR, f32x4& PI)
{
    do_phase1<L, TRI_L1[L][IDX], TRI_L2[L][IDX]>(sh_fh, frag, tid);
    do_mfma<L>(frag, wh, IDX * 256, wave, lane, PR, PI);
    // Compile-time scheduling fence: keep each step's live ranges bounded.
    // Without it the compiler hoists all steps' global w-loads to the top
    // -> ~25KB/block scratch spill (round 8: FETCH 6->27MB, WRITE 1->38MB).
    __builtin_amdgcn_sched_barrier(0);
}

template <int L, int... Is>
__device__ __forceinline__ void run_steps(std::integer_sequence<int, Is...>,
    const unsigned* sh_fh, char* frag, const unsigned short* wh,
    int tid, int wave, int lane, f32x4& PR, f32x4& PI)
{
    (step<L, Is>(sh_fh, frag, wh, tid, wave, lane, PR, PI), ...);
}

template <int L>
__device__ void run_l(const float* const* fs, const unsigned short* __restrict__ wh,
                      float* __restrict__ out, unsigned* sh_fh, char* frag, float* pb)
{
    const int b = blockIdx.x, tid = threadIdx.x;
    const int wave = tid >> 6, lane = tid & 63;

    // stage all f_l[b] into LDS as packed f16 complex (576 u32)
#pragma unroll
    for (int l = 0; l < 6; ++l) {
        const int cnt = 16 * (2 * l + 1);               // complex elements
        const float2* s2 = (const float2*)(fs[l] + (size_t)b * 32 * (2 * l + 1));
        if (tid < cnt) {
            const float2 v = s2[tid];
            const __half2 h = __floats2half2_rn(v.x, v.y);
            sh_fh[FOFFH_[l] + tid] = *(const unsigned*)&h;
        }
    }
    __syncthreads();

    f32x4 PR = {0.f, 0.f, 0.f, 0.f}, PI = {0.f, 0.f, 0.f, 0.f};

    run_steps<L>(std::make_integer_sequence<int, TRI_N[L]>{},
                 sh_fh, frag, wh, tid, wave, lane, PR, PI);

    // ---- epilogue: 4-wave partial sums via separate LDS region ----
    constexpr int NK = 2 * L + 1;
    {
        const int kcol = lane & 15, g = lane >> 4;   // D: col=lane&15 (k), row=4g+r (t)
#pragma unroll
        for (int r = 0; r < 4; ++r) {
            pb[(wave * 2 + 0) * 256 + (4 * g + r) * 16 + kcol] = PR[r];
            pb[(wave * 2 + 1) * 256 + (4 * g + r) * 16 + kcol] = PI[r];
        }
    }
    __syncthreads();

    if (tid < 16 * NK) {
        const int t = tid & 15, k = tid >> 4;
        float oR = 0.f, oI = 0.f;
#pragma unroll
        for (int w = 0; w < 4; ++w) {
            oR += pb[(w * 2 + 0) * 256 + t * 16 + k];
            oI += pb[(w * 2 + 1) * 256 + t * 16 + k];
        }
        float* op = out + OUTOFF_[L] + ((size_t)(b * 16 + t) * NK + k) * 2;
        op[0] = oR;
        op[1] = oI;
    }
}

__global__ __launch_bounds__(256, 4)
void update_kernel(const float* __restrict__ f0, const float* __restrict__ f1,
                   const float* __restrict__ f2, const float* __restrict__ f3,
                   const float* __restrict__ f4, const float* __restrict__ f5,
                   const unsigned short* __restrict__ wh,
                   float* __restrict__ out)
{
    __shared__ unsigned sh_fh[576];
    __shared__ __align__(16) char frag[11264];   // 11 rows x 1KB, single buffer
    __shared__ __align__(16) float pb[2048];     // epilogue partials (8KB)
    const float* fs[6] = {f0, f1, f2, f3, f4, f5};
    // Heavy-L-first dispatch: y=0 (dispatched first) -> L=5, ... y=5 -> L=0
    switch (blockIdx.y) {
        case 0: run_l<5>(fs, wh + WOFF_[5], out, sh_fh, frag, pb); break;
        case 1: run_l<4>(fs, wh + WOFF_[4], out, sh_fh, frag, pb); break;
        case 2: run_l<3>(fs, wh + WOFF_[3], out, sh_fh, frag, pb); break;
        case 3: run_l<2>(fs, wh + WOFF_[2], out, sh_fh, frag, pb); break;
        case 4: run_l<1>(fs, wh + WOFF_[1], out, sh_fh, frag, pb); break;
        default: run_l<0>(fs, wh + WOFF_[0], out, sh_fh, frag, pb); break;
    }
}

// ============================================================================
extern "C" void kernel_launch(void* const* d_in, const int* in_sizes, int n_in,
                              void* d_out, int out_size, void* d_ws, size_t ws_size,
                              hipStream_t stream)
{
    const float* f[6];
    const float* w[6];
    for (int l = 0; l < 6; ++l) {
        f[l] = (const float*)d_in[2 * l];      // f0,w0,f1,w1,... dict order
        w[l] = (const float*)d_in[2 * l + 1];
    }
    unsigned short* wh = (unsigned short*)d_ws;  // 565248 f16 = 1.13 MB

    // convert w to f16 (max segment 114688 f32 -> 112 blocks of 256x4)
    wconv_kernel<<<dim3(112, 6), dim3(256), 0, stream>>>(
        w[0], w[1], w[2], w[3], w[4], w[5], wh);

    update_kernel<<<dim3(256, 6), dim3(256), 0, stream>>>(
        f[0], f[1], f[2], f[3], f[4], f[5], wh, (float*)d_out);
}